// Round 1
// baseline (148.786 us; speedup 1.0000x reference)
//
#include <hip/hip_runtime.h>

// RoIAlign forward, torchvision semantics (aligned=false), fp32.
// N=2, C=256, H=200, W=200, K=1000 rois, pooled 7x7, sampling_ratio=2.
constexpr int Nn = 2, Cc = 256, Hh = 200, Ww = 200, Kk = 1000;
constexpr int PH = 7, PW = 7, SR = 2;
constexpr float SCALE = 0.25f;
constexpr int HWsz = Hh * Ww;

// ---------------------------------------------------------------------------
// NCHW -> NHWC transpose. Per batch: transpose a C x HW matrix to HW x C.
// 64x64 tiles staged through LDS; both global read and write coalesced.
// ---------------------------------------------------------------------------
__global__ __launch_bounds__(256) void transpose_nchw_nhwc(
    const float* __restrict__ in, float* __restrict__ out) {
  __shared__ float tile[64][65];  // +1 pad: conflict-free on both phases
  const int hw0 = blockIdx.x * 64;
  const int c0  = blockIdx.y * 64;
  const int b   = blockIdx.z;
  const int lane = threadIdx.x & 63;
  const int row  = threadIdx.x >> 6;  // 0..3

#pragma unroll
  for (int i = 0; i < 16; ++i) {
    const int cc = row + i * 4;
    tile[cc][lane] = in[(size_t)(b * Cc + c0 + cc) * HWsz + hw0 + lane];
  }
  __syncthreads();
#pragma unroll
  for (int i = 0; i < 16; ++i) {
    const int hh = row + i * 4;
    out[((size_t)b * HWsz + hw0 + hh) * Cc + c0 + lane] = tile[lane][hh];
  }
}

// ---------------------------------------------------------------------------
// RoI align. One block per roi; thread = channel. With NHWC=true, each of
// the 4 bilinear gathers per sample point is a contiguous 1KB read across
// the 256 threads (perfect coalescing). RoI params are block-uniform so the
// validity branches do not diverge within a wave.
// ---------------------------------------------------------------------------
template <bool NHWC>
__global__ __launch_bounds__(256) void roi_align_k(
    const float* __restrict__ feat, const float* __restrict__ rois,
    float* __restrict__ out) {
  const int k = blockIdx.x;
  const int c = threadIdx.x;

  const float* r = rois + k * 5;
  const int b = (int)r[0];
  const float x1 = r[1] * SCALE;
  const float y1 = r[2] * SCALE;
  const float x2 = r[3] * SCALE;
  const float y2 = r[4] * SCALE;
  const float roi_w = fmaxf(x2 - x1, 1.0f);
  const float roi_h = fmaxf(y2 - y1, 1.0f);
  const float bin_w = roi_w * (1.0f / PW);
  const float bin_h = roi_h * (1.0f / PH);

  // Base address for this (batch, channel).
  const size_t base_b = NHWC ? ((size_t)b * HWsz * Cc + c)
                             : ((size_t)(b * Cc + c) * HWsz);

  auto LD = [&](int y, int x) -> float {
    if (NHWC)
      return feat[base_b + (size_t)(y * Ww + x) * Cc];
    else
      return feat[base_b + y * Ww + x];
  };

  float* o = out + ((size_t)k * Cc + c) * (PH * PW);

  for (int ph = 0; ph < PH; ++ph) {
    float acc[PW];
#pragma unroll
    for (int i = 0; i < PW; ++i) acc[i] = 0.0f;

#pragma unroll
    for (int iy = 0; iy < SR; ++iy) {
      const float y = y1 + ((float)ph + ((float)iy + 0.5f) * (1.0f / SR)) * bin_h;
      const bool vy = (y >= -1.0f) && (y <= (float)Hh);
      const float cy = fmaxf(y, 0.0f);
      int yl = (int)cy;  // cy >= 0, trunc == floor
      int yh;
      float fy;
      if (yl >= Hh - 1) {
        yl = Hh - 1; yh = Hh - 1; fy = 0.0f;
      } else {
        yh = yl + 1; fy = cy - (float)yl;
      }
      const float wyl = 1.0f - fy;
      const float wyh = fy;

#pragma unroll
      for (int pw = 0; pw < PW; ++pw) {
#pragma unroll
        for (int ix = 0; ix < SR; ++ix) {
          const float x = x1 + ((float)pw + ((float)ix + 0.5f) * (1.0f / SR)) * bin_w;
          const bool vx = (x >= -1.0f) && (x <= (float)Ww);
          const float cx = fmaxf(x, 0.0f);
          int xl = (int)cx;
          int xh;
          float fx;
          if (xl >= Ww - 1) {
            xl = Ww - 1; xh = Ww - 1; fx = 0.0f;
          } else {
            xh = xl + 1; fx = cx - (float)xl;
          }
          const float wxl = 1.0f - fx;
          const float wxh = fx;

          if (vy && vx) {  // block-uniform branch
            const float v00 = LD(yl, xl);
            const float v01 = LD(yl, xh);
            const float v10 = LD(yh, xl);
            const float v11 = LD(yh, xh);
            acc[pw] += wyl * (wxl * v00 + wxh * v01) +
                       wyh * (wxl * v10 + wxh * v11);
          }
        }
      }
    }

#pragma unroll
    for (int pw = 0; pw < PW; ++pw) {
      o[ph * PW + pw] = acc[pw] * (1.0f / (SR * SR));
    }
  }
}

extern "C" void kernel_launch(void* const* d_in, const int* in_sizes, int n_in,
                              void* d_out, int out_size, void* d_ws, size_t ws_size,
                              hipStream_t stream) {
  const float* inp  = (const float*)d_in[0];   // (2,256,200,200) fp32
  const float* rois = (const float*)d_in[1];   // (1000,5) fp32
  float* out = (float*)d_out;                  // (1000,256,7,7) fp32

  const size_t nhwc_bytes = (size_t)Nn * Cc * HWsz * sizeof(float);
  if (ws_size >= nhwc_bytes) {
    float* nhwc = (float*)d_ws;
    transpose_nchw_nhwc<<<dim3(HWsz / 64, Cc / 64, Nn), 256, 0, stream>>>(inp, nhwc);
    roi_align_k<true><<<dim3(Kk), 256, 0, stream>>>(nhwc, rois, out);
  } else {
    // Scratch too small for the NHWC copy: gather directly from NCHW.
    roi_align_k<false><<<dim3(Kk), 256, 0, stream>>>(inp, rois, out);
  }
}